// Round 1
// baseline (436.718 us; speedup 1.0000x reference)
//
#include <hip/hip_runtime.h>
#include <math.h>

// Problem constants (fixed by setup_inputs)
#define BB    16      // batch
#define CC    64      // channels
#define HW    441     // h*w = 21*21
#define NCLS  10      // n_classes
#define MM    2205    // shot * h*w
#define NCHUNK 7
#define MCHUNK 315    // 2205 / 7

// ---------------- normalize queries: x1[b][c][p] -> qn[b][p][c] ----------------
__global__ void norm_q(const float* __restrict__ x1, float* __restrict__ qn) {
    int idx = blockIdx.x * blockDim.x + threadIdx.x;
    if (idx >= BB * HW) return;
    int b = idx / HW, p = idx % HW;
    const float* src = x1 + (size_t)b * CC * HW + p;
    float ss = 0.f;
    #pragma unroll
    for (int c = 0; c < CC; ++c) { float v = src[(size_t)c * HW]; ss += v * v; }
    float inv = 1.f / fmaxf(sqrtf(ss), 1e-12f);
    float* dst = qn + (size_t)idx * CC;
    #pragma unroll
    for (int c = 0; c < CC; ++c) dst[c] = src[(size_t)c * HW] * inv;
}

// ---------------- normalize supports: x2[n][c][m] -> sn[n][m][c] ----------------
__global__ void norm_s(const float* __restrict__ x2, float* __restrict__ sn) {
    int idx = blockIdx.x * blockDim.x + threadIdx.x;
    if (idx >= NCLS * MM) return;
    int n = idx / MM, m = idx % MM;
    const float* src = x2 + (size_t)n * CC * MM + m;
    float ss = 0.f;
    #pragma unroll
    for (int c = 0; c < CC; ++c) { float v = src[(size_t)c * MM]; ss += v * v; }
    float inv = 1.f / fmaxf(sqrtf(ss), 1e-12f);
    float* dst = sn + (size_t)idx * CC;
    #pragma unroll
    for (int c = 0; c < CC; ++c) dst[c] = src[(size_t)c * MM] * inv;
}

// ------- per-(b,n,chunk) block: each thread owns one query, top-3 over chunk -------
__global__ __launch_bounds__(448) void topk_chunk(const float* __restrict__ qn,
                                                  const float* __restrict__ sn,
                                                  float* __restrict__ partial) {
    int bn    = blockIdx.x / NCHUNK;   // b*NCLS + n
    int chunk = blockIdx.x % NCHUNK;
    int b = bn / NCLS, n = bn % NCLS;
    int q = threadIdx.x;
    if (q >= HW) return;

    // query vector in registers (64 floats = 16 float4)
    float4 qr[16];
    const float4* qp = (const float4*)(qn + ((size_t)(b * HW + q)) * CC);
    #pragma unroll
    for (int i = 0; i < 16; ++i) qr[i] = qp[i];

    float t0 = -1.0e30f, t1 = -1.0e30f, t2 = -1.0e30f;
    const float4* sp = (const float4*)(sn + ((size_t)(n * MM + chunk * MCHUNK)) * CC);

    for (int m = 0; m < MCHUNK; ++m) {
        float d = 0.f;
        #pragma unroll
        for (int i = 0; i < 16; ++i) {
            float4 s4 = sp[(size_t)m * 16 + i];
            d += qr[i].x * s4.x;
            d += qr[i].y * s4.y;
            d += qr[i].z * s4.z;
            d += qr[i].w * s4.w;
        }
        // branchless top-3 insert (t0 >= t1 >= t2 invariant not required, just the set)
        float a  = fmaxf(d, t0);
        float lo = fminf(d, t0);
        float c1 = fmaxf(lo, t1);
        float l1 = fminf(lo, t1);
        float c2 = fmaxf(l1, t2);
        t0 = a; t1 = c1; t2 = c2;
    }
    float* pp = partial + (((size_t)blockIdx.x) * HW + q) * 3;
    pp[0] = t0; pp[1] = t1; pp[2] = t2;
}

// ------- per-(b,n) block: merge 7 chunk top-3s per query, reduce-sum over queries -------
__global__ __launch_bounds__(512) void merge_reduce(const float* __restrict__ partial,
                                                    float* __restrict__ out) {
    __shared__ float red[512];
    int bn = blockIdx.x;
    int q  = threadIdx.x;
    float s = 0.f;
    if (q < HW) {
        float t0 = -1.0e30f, t1 = -1.0e30f, t2 = -1.0e30f;
        #pragma unroll
        for (int ch = 0; ch < NCHUNK; ++ch) {
            const float* pp = partial + (((size_t)(bn * NCHUNK + ch)) * HW + q) * 3;
            #pragma unroll
            for (int j = 0; j < 3; ++j) {
                float d  = pp[j];
                float a  = fmaxf(d, t0);
                float lo = fminf(d, t0);
                float c1 = fmaxf(lo, t1);
                float l1 = fminf(lo, t1);
                float c2 = fmaxf(l1, t2);
                t0 = a; t1 = c1; t2 = c2;
            }
        }
        s = t0 + t1 + t2;
    }
    red[q] = s;
    __syncthreads();
    #pragma unroll
    for (int stride = 256; stride >= 1; stride >>= 1) {
        if (q < stride) red[q] += red[q + stride];
        __syncthreads();
    }
    if (q == 0) out[bn] = red[0];
}

extern "C" void kernel_launch(void* const* d_in, const int* in_sizes, int n_in,
                              void* d_out, int out_size, void* d_ws, size_t ws_size,
                              hipStream_t stream) {
    const float* x1 = (const float*)d_in[0];   // [16,64,21,21]
    const float* x2 = (const float*)d_in[1];   // [10,64,2205]
    float* out = (float*)d_out;                // [16,10]

    float* ws      = (float*)d_ws;
    float* qn      = ws;                                   // 16*441*64   = 451584
    float* sn      = qn + (size_t)BB * HW * CC;            // 10*2205*64  = 1411200
    float* partial = sn + (size_t)NCLS * MM * CC;          // 1120*441*3  = 1481760

    norm_q<<<(BB * HW + 255) / 256, 256, 0, stream>>>(x1, qn);
    norm_s<<<(NCLS * MM + 255) / 256, 256, 0, stream>>>(x2, sn);
    topk_chunk<<<BB * NCLS * NCHUNK, 448, 0, stream>>>(qn, sn, partial);
    merge_reduce<<<BB * NCLS, 512, 0, stream>>>(partial, out);
}

// Round 2
// 127.422 us; speedup vs baseline: 3.4273x; 3.4273x over previous
//
#include <hip/hip_runtime.h>
#include <math.h>

// Problem constants
#define BB    16      // batch
#define CC    64      // channels
#define HW    441     // h*w
#define QP    448     // HW padded to 28 tiles of 16
#define NCLS  10
#define MM    2205
#define MP    2208    // MM padded to 138 tiles of 16
#define NQT   28      // query tiles
#define NMT   138     // m tiles
#define CHUNK_T 6     // m-tiles per LDS chunk
#define NCHUNKS 23    // 138 / 6

typedef _Float16 half8 __attribute__((ext_vector_type(8)));
typedef float   float4_ __attribute__((ext_vector_type(4)));

// sorted top-3 insert: (a0>=a1>=a2) -> insert d, 5 ops
__device__ __forceinline__ void ins3(float d, float& a0, float& a1, float& a2) {
    float m0 = fmaxf(d, a0);
    float lo = fminf(d, a0);
    float m1 = fmaxf(lo, a1);
    float l1 = fminf(lo, a1);
    float m2 = fmaxf(l1, a2);
    a0 = m0; a1 = m1; a2 = m2;
}

// ---- normalize queries: x1[b][c][p] -> qn[b][qp][c] fp16, zero-padded q ----
__global__ void norm_q(const float* __restrict__ x1, _Float16* __restrict__ qn) {
    int idx = blockIdx.x * blockDim.x + threadIdx.x;
    if (idx >= BB * QP) return;
    int b = idx / QP, p = idx % QP;
    _Float16* dst = qn + (size_t)idx * CC;
    if (p >= HW) {
        #pragma unroll
        for (int c = 0; c < CC; ++c) dst[c] = (_Float16)0.f;
        return;
    }
    const float* src = x1 + (size_t)b * CC * HW + p;
    float ss = 0.f;
    #pragma unroll
    for (int c = 0; c < CC; ++c) { float v = src[(size_t)c * HW]; ss += v * v; }
    float inv = 1.f / fmaxf(sqrtf(ss), 1e-12f);
    #pragma unroll
    for (int c = 0; c < CC; ++c) dst[c] = (_Float16)(src[(size_t)c * HW] * inv);
}

// ---- normalize supports: x2[n][c][m] -> sn[n][mp][c] fp16, zero-padded m ----
__global__ void norm_s(const float* __restrict__ x2, _Float16* __restrict__ sn) {
    int idx = blockIdx.x * blockDim.x + threadIdx.x;
    if (idx >= NCLS * MP) return;
    int n = idx / MP, m = idx % MP;
    _Float16* dst = sn + (size_t)idx * CC;
    if (m >= MM) {
        #pragma unroll
        for (int c = 0; c < CC; ++c) dst[c] = (_Float16)0.f;
        return;
    }
    const float* src = x2 + (size_t)n * CC * MM + m;
    float ss = 0.f;
    #pragma unroll
    for (int c = 0; c < CC; ++c) { float v = src[(size_t)c * MM]; ss += v * v; }
    float inv = 1.f / fmaxf(sqrtf(ss), 1e-12f);
    #pragma unroll
    for (int c = 0; c < CC; ++c) dst[c] = (_Float16)(src[(size_t)c * MM] * inv);
}

__global__ void zero_out(float* out) {
    int i = blockIdx.x * blockDim.x + threadIdx.x;
    if (i < BB * NCLS) out[i] = 0.f;
}

// ---- main: per-(b,n,qgroup) block, 4 waves x 1 q-tile each, sweep m with MFMA ----
__global__ __launch_bounds__(256) void img2class_mfma(const _Float16* __restrict__ qn,
                                                      const _Float16* __restrict__ sn,
                                                      float* __restrict__ out) {
    __shared__ _Float16 lds[CHUNK_T * 16 * CC];   // 96 rows x 64 halves = 12 KB
    __shared__ float red[16];

    int bn = blockIdx.x / 7, qg = blockIdx.x % 7;
    int b = bn / NCLS, n = bn % NCLS;
    int tid  = threadIdx.x;
    int wave = tid >> 6, lane = tid & 63;
    int col  = lane & 15, quad = lane >> 4;
    int qt = qg * 4 + wave;        // 0..27
    int q0 = qt * 16;

    // A fragments: A[m=col][k=quad*8+j], k-halves 0 and 1 (channels 0-31, 32-63)
    const half8* Ap = (const half8*)(qn + ((size_t)(b * QP + q0 + col)) * CC + quad * 8);
    half8 A0 = Ap[0];
    half8 A1 = Ap[4];              // +32 halves

    float t0[4], t1[4], t2[4];
    #pragma unroll
    for (int r = 0; r < 4; ++r) { t0[r] = -1.0e30f; t1[r] = -1.0e30f; t2[r] = -1.0e30f; }

    // last m-tile (137): real m only for col < 13 (2205 = 137*16 + 13)
    float pen = (col >= (MM - 137 * 16)) ? -1.0e30f : 0.0f;

    const _Float16* sbase = sn + (size_t)n * MP * CC;

    for (int chunk = 0; chunk < NCHUNKS; ++chunk) {
        __syncthreads();
        // stage 96 support rows: 768 pieces of 8 halves, 3 per thread, XOR-swizzled
        #pragma unroll
        for (int i = 0; i < 3; ++i) {
            int p   = tid + i * 256;
            int row = p >> 3, pc = p & 7;
            half8 v = *(const half8*)(sbase + ((size_t)(chunk * 96 + row)) * CC + pc * 8);
            *(half8*)(&lds[row * CC + ((pc ^ (row & 7)) << 3)]) = v;
        }
        __syncthreads();
        #pragma unroll
        for (int t6 = 0; t6 < CHUNK_T; ++t6) {
            int mt = chunk * CHUNK_T + t6;
            int r  = t6 * 16 + col;
            half8 B0 = *(const half8*)(&lds[r * CC + ((quad       ^ (r & 7)) << 3)]);
            half8 B1 = *(const half8*)(&lds[r * CC + (((4 + quad) ^ (r & 7)) << 3)]);
            float4_ z = {0.f, 0.f, 0.f, 0.f};
            float4_ acc = __builtin_amdgcn_mfma_f32_16x16x32_f16(A0, B0, z, 0, 0, 0);
            acc = __builtin_amdgcn_mfma_f32_16x16x32_f16(A1, B1, acc, 0, 0, 0);
            if (mt == NMT - 1) { acc.x += pen; acc.y += pen; acc.z += pen; acc.w += pen; }
            ins3(acc.x, t0[0], t1[0], t2[0]);
            ins3(acc.y, t0[1], t1[1], t2[1]);
            ins3(acc.z, t0[2], t1[2], t2[2]);
            ins3(acc.w, t0[3], t1[3], t2[3]);
        }
    }

    // merge top-3 across the 16 lanes (m-columns) sharing each q row
    #pragma unroll
    for (int step = 1; step <= 8; step <<= 1) {
        #pragma unroll
        for (int r = 0; r < 4; ++r) {
            float o0 = __shfl_xor(t0[r], step);
            float o1 = __shfl_xor(t1[r], step);
            float o2 = __shfl_xor(t2[r], step);
            ins3(o0, t0[r], t1[r], t2[r]);
            ins3(o1, t0[r], t1[r], t2[r]);
            ins3(o2, t0[r], t1[r], t2[r]);
        }
    }

    float s = 0.f;
    if (col == 0) {
        #pragma unroll
        for (int r = 0; r < 4; ++r) {
            int q = q0 + quad * 4 + r;
            if (q < HW) s += t0[r] + t1[r] + t2[r];
        }
        red[wave * 4 + quad] = s;
    }
    __syncthreads();
    if (tid == 0) {
        float tot = 0.f;
        #pragma unroll
        for (int i = 0; i < 16; ++i) tot += red[i];
        atomicAdd(out + bn, tot);
    }
}

extern "C" void kernel_launch(void* const* d_in, const int* in_sizes, int n_in,
                              void* d_out, int out_size, void* d_ws, size_t ws_size,
                              hipStream_t stream) {
    const float* x1 = (const float*)d_in[0];   // [16,64,21,21]
    const float* x2 = (const float*)d_in[1];   // [10,64,2205]
    float* out = (float*)d_out;                // [16,10]

    _Float16* qn = (_Float16*)d_ws;                            // 16*448*64
    _Float16* sn = qn + (size_t)BB * QP * CC;                  // 10*2208*64

    zero_out<<<1, 256, 0, stream>>>(out);
    norm_q<<<(BB * QP + 255) / 256, 256, 0, stream>>>(x1, qn);
    norm_s<<<(NCLS * MP + 255) / 256, 256, 0, stream>>>(x2, sn);
    img2class_mfma<<<BB * NCLS * 7, 256, 0, stream>>>(qn, sn, out);
}

// Round 3
// 111.382 us; speedup vs baseline: 3.9209x; 1.1440x over previous
//
#include <hip/hip_runtime.h>
#include <math.h>

// Problem constants
#define BB    16      // batch
#define CC    64      // channels
#define HW    441     // h*w
#define QP    448     // HW padded to 28 tiles of 16
#define NCLS  10
#define MM    2205
#define MP    2208    // MM padded to 138 tiles of 16
#define NMT   138     // m tiles
#define CHUNK_T 6     // m-tiles per LDS chunk
#define NCHUNKS 23    // 138 / 6
#define CHUNK_BYTES (CHUNK_T * 16 * CC * 2)   // 12288

typedef _Float16 half8 __attribute__((ext_vector_type(8)));
typedef float   float4_ __attribute__((ext_vector_type(4)));

// s_waitcnt with vmcnt(n), lgkmcnt/expcnt = no-wait  (gfx9 encoding)
#define WAIT_VMCNT(n) __builtin_amdgcn_s_waitcnt(0x0F70 | (n))

// async global->LDS 16B per lane; lds dest = uniform base + lane*16
#define GLDS16(g, l) __builtin_amdgcn_global_load_lds(                         \
    (const __attribute__((address_space(1))) unsigned int*)(const void*)(g),   \
    (__attribute__((address_space(3))) unsigned int*)(void*)(l), 16, 0, 0)

// sorted top-3 insert (a0>=a1>=a2), 4 ops via med3
__device__ __forceinline__ void ins3(float d, float& a0, float& a1, float& a2) {
    float n2 = fmaxf(fminf(d, a1), a2);
    float n1 = __builtin_amdgcn_fmed3f(d, a0, a1);
    float n0 = fmaxf(d, a0);
    a0 = n0; a1 = n1; a2 = n2;
}

// ---- fused prep: zero out + normalize queries (linear fp16) + supports
// (fp16, XOR-swizzled piece order within each 128B descriptor) ----
__global__ __launch_bounds__(256) void prep(const float* __restrict__ x1,
                                            const float* __restrict__ x2,
                                            _Float16* __restrict__ qn,
                                            _Float16* __restrict__ sn,
                                            float* __restrict__ out) {
    __shared__ float ssred[256];
    int tid = threadIdx.x;
    int ml = tid & 31, cg = tid >> 5;          // 32 descriptors x 8 c-groups
    float v[8];
    _Float16* dst;
    if (blockIdx.x < BB * 14) {                // query part: 16 b x 14 p-tiles of 32
        if (blockIdx.x == 0 && tid < BB * NCLS) out[tid] = 0.f;
        int b = blockIdx.x / 14, pt = blockIdx.x % 14;
        int p = pt * 32 + ml;
        const float* src = x1 + (size_t)b * CC * HW + p;
        bool real = p < HW;
        #pragma unroll
        for (int i = 0; i < 8; ++i) v[i] = real ? src[(size_t)(cg * 8 + i) * HW] : 0.f;
        dst = qn + ((size_t)(b * QP + p)) * CC + cg * 8;           // linear
    } else {                                   // support part: 10 n x 69 m-tiles of 32
        int sb = blockIdx.x - BB * 14;
        int n = sb / 69, mt = sb % 69;
        int m = mt * 32 + ml;
        const float* src = x2 + (size_t)n * CC * MM + m;
        bool real = m < MM;
        #pragma unroll
        for (int i = 0; i < 8; ++i) v[i] = real ? src[(size_t)(cg * 8 + i) * MM] : 0.f;
        dst = sn + ((size_t)(n * MP + m)) * CC + ((cg ^ (ml & 7)) * 8);  // swizzled
    }
    float ss = 0.f;
    #pragma unroll
    for (int i = 0; i < 8; ++i) ss += v[i] * v[i];
    ssred[tid] = ss;
    __syncthreads();
    float tot = 0.f;
    #pragma unroll
    for (int j = 0; j < 8; ++j) tot += ssred[j * 32 + ml];
    float inv = 1.f / fmaxf(sqrtf(tot), 1e-12f);
    half8 h;
    #pragma unroll
    for (int i = 0; i < 8; ++i) h[i] = (_Float16)(v[i] * inv);
    *(half8*)dst = h;
}

// ---- main: per-(b,n,qgroup) block, 4 waves x 1 q-tile, double-buffered async staging ----
__global__ __launch_bounds__(256) void img2class_mfma(const _Float16* __restrict__ qn,
                                                      const _Float16* __restrict__ sn,
                                                      float* __restrict__ out) {
    __shared__ half8 ldsv[2 * CHUNK_T * 16 * 8];   // 2 x 12KB, 16B-aligned
    __shared__ float red[16];
    _Float16* lds = (_Float16*)ldsv;

    int bn = blockIdx.x / 7, qg = blockIdx.x % 7;
    int b = bn / NCLS, n = bn % NCLS;
    int tid  = threadIdx.x;
    int wave = tid >> 6, lane = tid & 63;
    int col  = lane & 15, quad = lane >> 4;
    int q0 = (qg * 4 + wave) * 16;

    // A fragments: A[m=col][k=quad*8+j], channels 0-31 and 32-63
    const half8* Ap = (const half8*)(qn + ((size_t)(b * QP + q0 + col)) * CC + quad * 8);
    half8 A0 = Ap[0];
    half8 A1 = Ap[4];

    float t0[4], t1[4], t2[4];
    #pragma unroll
    for (int r = 0; r < 4; ++r) { t0[r] = -1.0e30f; t1[r] = -1.0e30f; t2[r] = -1.0e30f; }

    // last m-tile (137): real m only for col < 13 (2205 = 137*16 + 13)
    float pen = (col >= 13) ? -1.0e30f : 0.0f;

    const char* sbase = (const char*)(sn + (size_t)n * MP * CC);
    int so = (wave * 3) * 1024 + lane * 16;       // this wave's staging src offset
    char* lbase = (char*)lds;

    // prologue: chunk 0 -> buf 0
    #pragma unroll
    for (int i = 0; i < 3; ++i)
        GLDS16(sbase + so + i * 1024, lbase + (wave * 3 + i) * 1024);

    for (int chunk = 0; chunk < NCHUNKS; ++chunk) {
        if (chunk + 1 < NCHUNKS) {
            const char* g = sbase + (size_t)(chunk + 1) * CHUNK_BYTES + so;
            char* l = lbase + ((chunk + 1) & 1) * CHUNK_BYTES + (wave * 3) * 1024;
            #pragma unroll
            for (int i = 0; i < 3; ++i)
                GLDS16(g + i * 1024, l + i * 1024);
            WAIT_VMCNT(3);     // current chunk's 3 loads done; prefetch stays in flight
        } else {
            WAIT_VMCNT(0);
        }
        __builtin_amdgcn_s_barrier();

        const _Float16* lb = lds + (chunk & 1) * (CHUNK_T * 16 * CC);
        #pragma unroll
        for (int t6 = 0; t6 < CHUNK_T; ++t6) {
            int r = t6 * 16 + col;
            half8 B0 = *(const half8*)(lb + r * CC + ((quad       ^ (r & 7)) << 3));
            half8 B1 = *(const half8*)(lb + r * CC + (((4 + quad) ^ (r & 7)) << 3));
            float4_ z = {0.f, 0.f, 0.f, 0.f};
            float4_ acc = __builtin_amdgcn_mfma_f32_16x16x32_f16(A0, B0, z, 0, 0, 0);
            acc = __builtin_amdgcn_mfma_f32_16x16x32_f16(A1, B1, acc, 0, 0, 0);
            if (chunk == NCHUNKS - 1 && t6 == CHUNK_T - 1) {
                acc.x += pen; acc.y += pen; acc.z += pen; acc.w += pen;
            }
            ins3(acc.x, t0[0], t1[0], t2[0]);
            ins3(acc.y, t0[1], t1[1], t2[1]);
            ins3(acc.z, t0[2], t1[2], t2[2]);
            ins3(acc.w, t0[3], t1[3], t2[3]);
        }
        __syncthreads();   // release buffer (safe overwrite next iter); drains prefetch late
    }

    // merge top-3 across the 16 lanes (m-columns) sharing each q row
    #pragma unroll
    for (int step = 1; step <= 8; step <<= 1) {
        #pragma unroll
        for (int r = 0; r < 4; ++r) {
            float o0 = __shfl_xor(t0[r], step);
            float o1 = __shfl_xor(t1[r], step);
            float o2 = __shfl_xor(t2[r], step);
            ins3(o0, t0[r], t1[r], t2[r]);
            ins3(o1, t0[r], t1[r], t2[r]);
            ins3(o2, t0[r], t1[r], t2[r]);
        }
    }

    if (col == 0) {
        float s = 0.f;
        #pragma unroll
        for (int r = 0; r < 4; ++r) {
            int q = q0 + quad * 4 + r;
            if (q < HW) s += t0[r] + t1[r] + t2[r];
        }
        red[wave * 4 + quad] = s;
    }
    __syncthreads();
    if (tid == 0) {
        float tot = 0.f;
        #pragma unroll
        for (int i = 0; i < 16; ++i) tot += red[i];
        atomicAdd(out + bn, tot);
    }
}

extern "C" void kernel_launch(void* const* d_in, const int* in_sizes, int n_in,
                              void* d_out, int out_size, void* d_ws, size_t ws_size,
                              hipStream_t stream) {
    const float* x1 = (const float*)d_in[0];   // [16,64,21,21]
    const float* x2 = (const float*)d_in[1];   // [10,64,2205]
    float* out = (float*)d_out;                // [16,10]

    _Float16* qn = (_Float16*)d_ws;                  // 16*448*64 halves
    _Float16* sn = qn + (size_t)BB * QP * CC;        // 10*2208*64 halves, swizzled

    prep<<<BB * 14 + NCLS * 69, 256, 0, stream>>>(x1, x2, qn, sn, out);
    img2class_mfma<<<BB * NCLS * 7, 256, 0, stream>>>(qn, sn, out);
}

// Round 4
// 103.872 us; speedup vs baseline: 4.2044x; 1.0723x over previous
//
#include <hip/hip_runtime.h>
#include <math.h>

// Problem constants
#define BB    16      // batch
#define CC    64      // channels
#define HW    441     // h*w
#define QP    448     // HW padded to 28 tiles of 16
#define NCLS  10
#define MM    2205
#define MP    2208    // MM padded to 138 tiles of 16
#define CHUNK_T 6     // m-tiles per LDS chunk
#define CHUNK_BYTES (CHUNK_T * 16 * CC * 2)   // 12288
// m split: half0 = tiles [0,72) -> 12 chunks, half1 = tiles [72,138) -> 11 chunks

typedef _Float16 half8 __attribute__((ext_vector_type(8)));
typedef float   float4_ __attribute__((ext_vector_type(4)));

// s_waitcnt with vmcnt(n), lgkmcnt/expcnt = no-wait (gfx9 encoding)
#define WAIT_VMCNT(n) __builtin_amdgcn_s_waitcnt(0x0F70 | (n))

// async global->LDS 16B per lane; lds dest = uniform base + lane*16
#define GLDS16(g, l) __builtin_amdgcn_global_load_lds(                         \
    (const __attribute__((address_space(1))) unsigned int*)(const void*)(g),   \
    (__attribute__((address_space(3))) unsigned int*)(void*)(l), 16, 0, 0)

// sorted top-3 insert (a0>=a1>=a2): 3 ops via med3
__device__ __forceinline__ void ins3(float d, float& a0, float& a1, float& a2) {
    float n0 = fmaxf(d, a0);
    float n1 = __builtin_amdgcn_fmed3f(d, a0, a1);
    float n2 = __builtin_amdgcn_fmed3f(d, a1, a2);
    a0 = n0; a1 = n1; a2 = n2;
}

// ---- fused prep: normalize queries (linear fp16) + supports (fp16, XOR-swizzled
// piece order) with LDS-transposed fully-coalesced 4KB block stores ----
__global__ __launch_bounds__(256) void prep(const float* __restrict__ x1,
                                            const float* __restrict__ x2,
                                            _Float16* __restrict__ qn,
                                            _Float16* __restrict__ sn) {
    __shared__ float ssred[256];
    __shared__ half8 obuf[256];     // 32 descriptors x 8 pieces = 4KB
    int tid = threadIdx.x;
    int ml = tid & 31, cg = tid >> 5;     // 32 descriptors x 8 c-groups
    float v[8];
    half8* dstblk;
    int wz;
    if (blockIdx.x < BB * 14) {           // queries: 16 b x 14 p-tiles of 32
        int b = blockIdx.x / 14, pt = blockIdx.x % 14;
        int p = pt * 32 + ml;
        const float* src = x1 + (size_t)b * CC * HW + p;
        bool real = p < HW;
        #pragma unroll
        for (int i = 0; i < 8; ++i) v[i] = real ? src[(size_t)(cg * 8 + i) * HW] : 0.f;
        wz = cg;                                            // linear
        dstblk = (half8*)(qn + ((size_t)(b * QP + pt * 32)) * CC);
    } else {                              // supports: 10 n x 69 m-tiles of 32
        int sb = blockIdx.x - BB * 14;
        int n = sb / 69, mt = sb % 69;
        int m = mt * 32 + ml;
        const float* src = x2 + (size_t)n * CC * MM + m;
        bool real = m < MM;
        #pragma unroll
        for (int i = 0; i < 8; ++i) v[i] = real ? src[(size_t)(cg * 8 + i) * MM] : 0.f;
        wz = cg ^ (ml & 7);                                 // bank-swizzled piece
        dstblk = (half8*)(sn + ((size_t)(n * MP + mt * 32)) * CC);
    }
    float ss = 0.f;
    #pragma unroll
    for (int i = 0; i < 8; ++i) ss += v[i] * v[i];
    ssred[tid] = ss;
    __syncthreads();
    float tot = 0.f;
    #pragma unroll
    for (int j = 0; j < 8; ++j) tot += ssred[j * 32 + ml];
    float inv = 1.f / fmaxf(sqrtf(tot), 1e-12f);
    half8 h;
    #pragma unroll
    for (int i = 0; i < 8; ++i) h[i] = (_Float16)(v[i] * inv);
    obuf[ml * 8 + wz] = h;
    __syncthreads();
    dstblk[tid] = obuf[tid];              // 256 x 16B contiguous
}

// ---- main: per-(b,n,qgroup,mhalf) block, 4 waves x 1 q-tile, async double-buffer,
// pair-max + 3-op top-3 insert, per-query partial top-3 out ----
__global__ __launch_bounds__(256) void img2class_mfma(const _Float16* __restrict__ qn,
                                                      const _Float16* __restrict__ sn,
                                                      float* __restrict__ partial) {
    __shared__ half8 ldsv[2 * CHUNK_T * 16 * 8];   // 2 x 12KB
    _Float16* lds = (_Float16*)ldsv;

    int mh = blockIdx.x & 1;
    int t  = blockIdx.x >> 1;
    int bn = t / 7, qg = t % 7;
    int b = bn / NCLS, n = bn % NCLS;
    int nch    = mh ? 11 : 12;
    int mtile0 = mh ? 72 : 0;

    int tid  = threadIdx.x;
    int wave = tid >> 6, lane = tid & 63;
    int col  = lane & 15, quad = lane >> 4;
    int q0 = (qg * 4 + wave) * 16;

    // A fragments: A[m=col][k=quad*8+j], channels 0-31 and 32-63
    const half8* Ap = (const half8*)(qn + ((size_t)(b * QP + q0 + col)) * CC + quad * 8);
    half8 A0 = Ap[0];
    half8 A1 = Ap[4];

    float t0[4], t1[4], t2[4];
    #pragma unroll
    for (int r = 0; r < 4; ++r) { t0[r] = -1.0e30f; t1[r] = -1.0e30f; t2[r] = -1.0e30f; }

    // last m-tile (137, in half1): real m only for col < 13
    float pen = (col >= 13) ? -1.0e30f : 0.0f;

    const char* sbase = (const char*)(sn + (size_t)n * MP * CC) + (size_t)mtile0 * 16 * CC * 2;
    int so = (wave * 3) * 1024 + lane * 16;
    char* lbase = (char*)lds;

    // prologue: chunk 0 -> buf 0
    #pragma unroll
    for (int i = 0; i < 3; ++i)
        GLDS16(sbase + so + i * 1024, lbase + (wave * 3 + i) * 1024);

    // hoisted swizzled LDS offsets (r&7 == col&7 for every tile)
    int sw0 = ((0 ^ (col & 7)) << 3) + col * CC;   // piece quad..quad+? computed below
    (void)sw0;

    for (int chunk = 0; chunk < nch; ++chunk) {
        if (chunk + 1 < nch) {
            const char* g = sbase + (size_t)(chunk + 1) * CHUNK_BYTES + so;
            char* l = lbase + ((chunk + 1) & 1) * CHUNK_BYTES + (wave * 3) * 1024;
            #pragma unroll
            for (int i = 0; i < 3; ++i)
                GLDS16(g + i * 1024, l + i * 1024);
            WAIT_VMCNT(3);     // current chunk resident; prefetch stays in flight
        } else {
            WAIT_VMCNT(0);
        }
        __builtin_amdgcn_s_barrier();

        const _Float16* lb = lds + (chunk & 1) * (CHUNK_T * 16 * CC);
        bool lastc = (mh == 1) && (chunk == nch - 1);
        #pragma unroll
        for (int pr = 0; pr < 3; ++pr) {
            int re = (pr * 2) * 16 + col;
            int ro = (pr * 2 + 1) * 16 + col;
            half8 B0e = *(const half8*)(lb + re * CC + ((quad       ^ (col & 7)) << 3));
            half8 B1e = *(const half8*)(lb + re * CC + (((4 + quad) ^ (col & 7)) << 3));
            half8 B0o = *(const half8*)(lb + ro * CC + ((quad       ^ (col & 7)) << 3));
            half8 B1o = *(const half8*)(lb + ro * CC + (((4 + quad) ^ (col & 7)) << 3));
            float4_ z = {0.f, 0.f, 0.f, 0.f};
            float4_ ae = __builtin_amdgcn_mfma_f32_16x16x32_f16(A0, B0e, z, 0, 0, 0);
            ae = __builtin_amdgcn_mfma_f32_16x16x32_f16(A1, B1e, ae, 0, 0, 0);
            float4_ ao = __builtin_amdgcn_mfma_f32_16x16x32_f16(A0, B0o, z, 0, 0, 0);
            ao = __builtin_amdgcn_mfma_f32_16x16x32_f16(A1, B1o, ao, 0, 0, 0);
            if (lastc && pr == 2) { ao.x += pen; ao.y += pen; ao.z += pen; ao.w += pen; }
            // pair-max filter, then 3-op insert
            float d0 = fmaxf(ae.x, ao.x);
            float d1 = fmaxf(ae.y, ao.y);
            float d2 = fmaxf(ae.z, ao.z);
            float d3 = fmaxf(ae.w, ao.w);
            ins3(d0, t0[0], t1[0], t2[0]);
            ins3(d1, t0[1], t1[1], t2[1]);
            ins3(d2, t0[2], t1[2], t2[2]);
            ins3(d3, t0[3], t1[3], t2[3]);
        }
        __syncthreads();   // release buffer for next overwrite
    }

    // merge top-3 across the 16 lanes (m-columns) sharing each q row
    #pragma unroll
    for (int step = 1; step <= 8; step <<= 1) {
        #pragma unroll
        for (int r = 0; r < 4; ++r) {
            float o0 = __shfl_xor(t0[r], step);
            float o1 = __shfl_xor(t1[r], step);
            float o2 = __shfl_xor(t2[r], step);
            ins3(o0, t0[r], t1[r], t2[r]);
            ins3(o1, t0[r], t1[r], t2[r]);
            ins3(o2, t0[r], t1[r], t2[r]);
        }
    }

    // per-query partial top-3: pblk = ((bn*7+qg)*2+mh), 64 queries x 3 floats
    if (col == 0) {
        float* pp = partial + ((size_t)((bn * 7 + qg) * 2 + mh) * 64 + wave * 16 + quad * 4) * 3;
        #pragma unroll
        for (int r = 0; r < 4; ++r) {
            pp[r * 3 + 0] = t0[r];
            pp[r * 3 + 1] = t1[r];
            pp[r * 3 + 2] = t2[r];
        }
    }
}

// ---- merge the two m-halves per query, sum top-3, reduce over queries ----
__global__ __launch_bounds__(512) void merge_halves(const float* __restrict__ partial,
                                                    float* __restrict__ out) {
    __shared__ float red[512];
    int bn = blockIdx.x;
    int q  = threadIdx.x;
    float s = 0.f;
    if (q < HW) {
        int qg = q >> 6, ql = q & 63;
        const float* p0 = partial + ((size_t)((bn * 7 + qg) * 2 + 0) * 64 + ql) * 3;
        const float* p1 = partial + ((size_t)((bn * 7 + qg) * 2 + 1) * 64 + ql) * 3;
        float a0 = p0[0], a1 = p0[1], a2 = p0[2];
        ins3(p1[0], a0, a1, a2);
        ins3(p1[1], a0, a1, a2);
        ins3(p1[2], a0, a1, a2);
        s = a0 + a1 + a2;
    }
    red[q] = s;
    __syncthreads();
    #pragma unroll
    for (int stride = 256; stride >= 1; stride >>= 1) {
        if (q < stride) red[q] += red[q + stride];
        __syncthreads();
    }
    if (q == 0) out[bn] = red[0];
}

extern "C" void kernel_launch(void* const* d_in, const int* in_sizes, int n_in,
                              void* d_out, int out_size, void* d_ws, size_t ws_size,
                              hipStream_t stream) {
    const float* x1 = (const float*)d_in[0];   // [16,64,21,21]
    const float* x2 = (const float*)d_in[1];   // [10,64,2205]
    float* out = (float*)d_out;                // [16,10]

    _Float16* qn   = (_Float16*)d_ws;                  // 16*448*64 halves
    _Float16* sn   = qn + (size_t)BB * QP * CC;        // 10*2208*64 halves, swizzled
    float* partial = (float*)(sn + (size_t)NCLS * MP * CC);  // 2240*64*3 floats

    prep<<<BB * 14 + NCLS * 69, 256, 0, stream>>>(x1, x2, qn, sn);
    img2class_mfma<<<BB * NCLS * 7 * 2, 256, 0, stream>>>(qn, sn, partial);
    merge_halves<<<BB * NCLS, 512, 0, stream>>>(partial, out);
}